// Round 10
// baseline (392.857 us; speedup 1.0000x reference)
//
#include <hip/hip_runtime.h>
#include <cstdint>
#include <cstddef>

#define NTOK 8192
#define DMODEL 768
#define NEXP 16
#define HDIM 3072
#define CAP 640
#define BLDP 72   // LDS row stride (elems) for B tiles; 144B = 9*16B

typedef __attribute__((ext_vector_type(8))) short short8v;
typedef __attribute__((ext_vector_type(4))) float f32x4;

static __device__ __forceinline__ unsigned short f2bf(float f){
  union { float f; unsigned int u; } v; v.f = f;
  unsigned int u = v.u;
  unsigned int r = (u + 0x7FFFu + ((u >> 16) & 1u)) >> 16;
  return (unsigned short)r;
}
// round-half-up pack: 0.5-ulp bound like RTNE (differs only on exact ties),
// ~3 VALU per 2 elems (merge pattern-matches to v_perm_b32). Plain C = sinkable.
static __device__ __forceinline__ unsigned int pk2b(float a, float b){
  unsigned int ua = __builtin_bit_cast(unsigned int, a) + 0x8000u;
  unsigned int ub = __builtin_bit_cast(unsigned int, b) + 0x8000u;
  return (ua >> 16) | (ub & 0xFFFF0000u);
}

// async global(16B per lane) -> LDS (wave-uniform base + lane*16)
static __device__ __forceinline__ void gload16(const unsigned short* g, unsigned short* l){
  __builtin_amdgcn_global_load_lds(
      (const __attribute__((address_space(1))) unsigned int*)g,
      (__attribute__((address_space(3))) unsigned int*)l, 16, 0, 0);
}

// ---------------- init expert_tok = -1 ----------------
__global__ void init_tok_kernel(int* __restrict__ expert_tok){
  int i = blockIdx.x * 256 + threadIdx.x;   // 40*256 = 10240 exact
  expert_tok[i] = -1;
}

// ---------------- router: logits, softmax-gate, argmax ----------------
__global__ __launch_bounds__(256) void router_kernel(
    const float* __restrict__ x, const float* __restrict__ Wr,
    int* __restrict__ eid, float* __restrict__ gate)
{
  int t = blockIdx.x * 4 + (threadIdx.x >> 6);
  int lane = threadIdx.x & 63;
  const float* xr = x + (size_t)t * DMODEL;
  float acc[16];
  #pragma unroll
  for (int e = 0; e < 16; e++) acc[e] = 0.f;
  #pragma unroll
  for (int i = 0; i < 12; i++){
    float xv = xr[lane + i * 64];
    const float* wrow = Wr + (size_t)(lane + i * 64) * 16;
    #pragma unroll
    for (int e = 0; e < 16; e++) acc[e] += xv * wrow[e];
  }
  #pragma unroll
  for (int e = 0; e < 16; e++){
    float v = acc[e];
    #pragma unroll
    for (int off = 32; off >= 1; off >>= 1) v += __shfl_xor(v, off, 64);
    acc[e] = v;
  }
  if (lane == 0){
    float mx = acc[0]; int bi = 0;
    #pragma unroll
    for (int e = 1; e < 16; e++) if (acc[e] > mx){ mx = acc[e]; bi = e; }
    float s = 0.f;
    #pragma unroll
    for (int e = 0; e < 16; e++) s += __expf(acc[e] - mx);
    eid[t] = bi;
    gate[t] = 1.0f / s;   // softmax value at the argmax
  }
}

// ---------------- order-preserving slot scan (1 block) ----------------
__global__ __launch_bounds__(256) void scan_route_kernel(
    const int* __restrict__ eid, const float* __restrict__ gate,
    int* __restrict__ expert_tok, float* __restrict__ cw, int* __restrict__ dropped)
{
  __shared__ int hist[256][16];
  int t = threadIdx.x;
  #pragma unroll
  for (int e = 0; e < 16; e++) hist[t][e] = 0;
  __syncthreads();
  for (int i = 0; i < 32; i++){
    int tok = t * 32 + i;
    hist[t][eid[tok]]++;
  }
  __syncthreads();
  if (t < 16){
    int run = 0;
    for (int i = 0; i < 256; i++){ int c = hist[i][t]; hist[i][t] = run; run += c; }
  }
  __syncthreads();
  for (int i = 0; i < 32; i++){
    int tok = t * 32 + i;
    int e = eid[tok];
    int slot = hist[t][e]++;
    if (slot < CAP){
      expert_tok[e * CAP + slot] = tok;
      cw[e * CAP + slot] = gate[tok];
      dropped[tok] = 0;
    } else {
      dropped[tok] = 1;
    }
  }
}

// ---------------- gather x rows -> bf16 [E][C][D] ----------------
__global__ __launch_bounds__(192) void gather_x_kernel(
    const float* __restrict__ x, const int* __restrict__ expert_tok,
    unsigned short* __restrict__ xa)
{
  int ec = blockIdx.x;
  int token = expert_tok[ec];
  int t4 = threadIdx.x * 4;
  ushort4 o;
  if (token >= 0){
    const float4 v = *(const float4*)(x + (size_t)token * DMODEL + t4);
    o.x = f2bf(v.x); o.y = f2bf(v.y); o.z = f2bf(v.z); o.w = f2bf(v.w);
  } else {
    o.x = 0; o.y = 0; o.z = 0; o.w = 0;
  }
  *(ushort4*)(xa + (size_t)ec * DMODEL + t4) = o;
}

// ---- B staging, 64x64 f32 tile, 256 threads: thread (nq=tid&15, kq=tid>>4)
// covers cols nq*4..+4, rows kq*4..+4. Writes b64 at chunk (kq>>1)^((R>>3)&7)
// (2-way = free); b128 reads conflict-free with cx = (kk*4+kg)^((R>>3)&7).
static __device__ __forceinline__ void stage64_load(
    const float* __restrict__ g, int ldg, uint2* p, int nq, int kq)
{
  const float* s = g + (size_t)(kq * 4) * ldg + (size_t)nq * 4;
  float4 r0 = *(const float4*)(s);
  float4 r1 = *(const float4*)(s + ldg);
  float4 r2 = *(const float4*)(s + 2 * ldg);
  float4 r3 = *(const float4*)(s + 3 * ldg);
  p[0].x = pk2b(r0.x, r1.x); p[0].y = pk2b(r2.x, r3.x);
  p[1].x = pk2b(r0.y, r1.y); p[1].y = pk2b(r2.y, r3.y);
  p[2].x = pk2b(r0.z, r1.z); p[2].y = pk2b(r2.z, r3.z);
  p[3].x = pk2b(r0.w, r1.w); p[3].y = pk2b(r2.w, r3.w);
}
static __device__ __forceinline__ void stage64_write(
    const uint2* p, unsigned short* __restrict__ lds, int nq, int kq)
{
  #pragma unroll
  for (int j = 0; j < 4; j++){
    int R = nq * 4 + j;
    int c8 = (kq >> 1) ^ ((R >> 3) & 7);
    *(uint2*)(lds + R * BLDP + c8 * 8 + (kq & 1) * 4) = p[j];
  }
}

// ---- B staging for gemm2 (128 stager threads): cols nq*4..+4, rows kq*8..+8 ----
template<int NQ>
static __device__ __forceinline__ void stageB8_load(
    const float* __restrict__ g, int ldg, uint4* p, int tid)
{
  const int nq = tid % NQ, kq = tid / NQ;
  const float* s = g + (size_t)(kq * 8) * ldg + (size_t)nq * 4;
  float4 r[8];
  #pragma unroll
  for (int i = 0; i < 8; i++) r[i] = *(const float4*)(s + (size_t)i * ldg);
  #pragma unroll
  for (int j = 0; j < 4; j++){
    p[j].x = pk2b(((const float*)&r[0])[j], ((const float*)&r[1])[j]);
    p[j].y = pk2b(((const float*)&r[2])[j], ((const float*)&r[3])[j]);
    p[j].z = pk2b(((const float*)&r[4])[j], ((const float*)&r[5])[j]);
    p[j].w = pk2b(((const float*)&r[6])[j], ((const float*)&r[7])[j]);
  }
}
template<int NQ>
static __device__ __forceinline__ void stageB8_write(
    const uint4* p, unsigned short* __restrict__ lds, int tid)
{
  const int nq = tid % NQ, kq = tid / NQ;
  #pragma unroll
  for (int j = 0; j < 4; j++){
    int R = nq * 4 + j;
    int c = kq ^ ((R >> 3) & 7);
    *(uint4*)(lds + R * BLDP + c * 8) = p[j];
  }
}

// ---------------- GEMM1: xa @ W1 (fused cvt) + swiglu -> act bf16 ----------------
// Narrow-n: 256 thr, block = 128m x (64 g + 64 u), LDS 34.4KB -> 4 blocks/CU.
__global__ __launch_bounds__(256, 4) void gemm1_swiglu_kernel(
    const unsigned short* __restrict__ xa,
    const float* __restrict__ W1,
    const float* __restrict__ b1,
    unsigned short* __restrict__ act)
{
  __shared__ unsigned short As [128 * 64];     // 16 KB
  __shared__ unsigned short Bgs[64 * BLDP];    // 9.2 KB
  __shared__ unsigned short Bus[64 * BLDP];    // 9.2 KB
  const int b = blockIdx.x;
  const int w = (b & 7) * 480 + (b >> 3);      // bijective XCD chunking (3840 = 8*480)
  const int mb = w % 5;
  const int nb = (w / 5) % 48;
  const int e  = w / 240;
  const int m0 = mb * 128;
  const int n0 = nb * 64;
  const int tid  = threadIdx.x;
  const int lane = tid & 63;
  const int wv   = tid >> 6;          // 0..3
  const int wr   = (wv >> 1) * 64;    // m-half
  const int wc   = (wv & 1) * 32;     // n-half of 64
  const int fr   = lane & 15;
  const int kg   = lane >> 4;
  const int cA   = fr & 7;            // A-read chunk XOR
  const int nq   = tid & 15;          // B-stage col group (16*4 = 64)
  const int kq   = tid >> 4;          // B-stage k group  (16*4 = 64)

  const unsigned short* Ag = xa + ((size_t)e * 640 + m0) * 768;
  const float* Bg = W1 + (size_t)e * 768 * 6144 + n0;
  const float* Bu = Bg + 3072;

  // A staging: linear LDS dest; global source chunk-XOR pre-swizzled (G21)
  const int srow = wv * 8 + (lane >> 3);
  const int scol = (((lane & 7) ^ ((lane >> 3) & 7)) * 8);
  unsigned short* ldsA = As + wv * 512;

  f32x4 accg[4][2], accu[4][2];
  f32x4 zero4 = {0.f, 0.f, 0.f, 0.f};
  #pragma unroll
  for (int m = 0; m < 4; m++)
    #pragma unroll
    for (int n = 0; n < 2; n++){ accg[m][n] = zero4; accu[m][n] = zero4; }

  uint2 pg[4], pu[4];
  stage64_load(Bg, 6144, pg, nq, kq);
  stage64_load(Bu, 6144, pu, nq, kq);

  for (int kt = 0; kt < 768; kt += 64){
    if (kt) __syncthreads();           // previous compute's LDS reads done
    stage64_write(pg, Bgs, nq, kq);
    stage64_write(pu, Bus, nq, kq);
    #pragma unroll
    for (int c = 0; c < 4; c++){
      int r = c * 32 + srow;
      gload16(Ag + (size_t)r * 768 + kt + scol, ldsA + c * 2048);
    }
    __syncthreads();                   // drains vmcnt (A) + lgkm (B writes)
    if (kt + 64 < 768){                // prefetch next B during MFMA phase
      stage64_load(Bg + (size_t)(kt + 64) * 6144, 6144, pg, nq, kq);
      stage64_load(Bu + (size_t)(kt + 64) * 6144, 6144, pu, nq, kq);
    }
    #pragma unroll
    for (int kk = 0; kk < 2; kk++){
      short8v af[4], bgf[2], buf[2];
      #pragma unroll
      for (int m = 0; m < 4; m++)
        af[m] = *(const short8v*)(As + (wr + m * 16 + fr) * 64 + (((kk * 4 + kg) ^ cA) * 8));
      #pragma unroll
      for (int n = 0; n < 2; n++){
        int R = wc + n * 16 + fr;
        int cx = (((kk * 4 + kg) ^ ((R >> 3) & 7)) * 8);
        bgf[n] = *(const short8v*)(Bgs + R * BLDP + cx);
        buf[n] = *(const short8v*)(Bus + R * BLDP + cx);
      }
      #pragma unroll
      for (int m = 0; m < 4; m++)
        #pragma unroll
        for (int n = 0; n < 2; n++){
          accg[m][n] = __builtin_amdgcn_mfma_f32_16x16x32_bf16(af[m], bgf[n], accg[m][n], 0, 0, 0);
          accu[m][n] = __builtin_amdgcn_mfma_f32_16x16x32_bf16(af[m], buf[n], accu[m][n], 0, 0, 0);
        }
    }
  }
  // epilogue: (+bias) -> silu(g)*u -> bf16 act
  #pragma unroll
  for (int n = 0; n < 2; n++){
    int col = n0 + wc + n * 16 + fr;
    float b_g = b1[(size_t)e * 6144 + col];
    float b_u = b1[(size_t)e * 6144 + 3072 + col];
    #pragma unroll
    for (int m = 0; m < 4; m++){
      #pragma unroll
      for (int r = 0; r < 4; r++){
        int row = m0 + wr + m * 16 + kg * 4 + r;
        float hg = accg[m][n][r] + b_g;
        float hu = accu[m][n][r] + b_u;
        float s = (hg / (1.0f + __expf(-hg))) * hu;
        act[((size_t)e * 640 + row) * 3072 + col] = f2bf(s);
      }
    }
  }
}

// ---------------- GEMM2: act @ W2 (fused cvt) + b2 -> y f32 ----------
__global__ __launch_bounds__(256, 4) void gemm2_kernel(
    const unsigned short* __restrict__ act,
    const float* __restrict__ W2,
    const float* __restrict__ b2,
    float* __restrict__ y)                   // [E][640][768]
{
  __shared__ unsigned short As[128 * 64];
  __shared__ unsigned short Bs[64 * BLDP];
  const int b = blockIdx.x;
  const int w = (b & 7) * 120 + (b >> 3);
  const int mb = w % 5;
  const int nb = (w / 5) % 12;
  const int e  = w / 60;
  const int m0 = mb * 128;
  const int n0 = nb * 64;
  const int tid  = threadIdx.x;
  const int lane = tid & 63;
  const int wv   = tid >> 6;
  const int wr   = (wv & 1) * 64;
  const int wc   = (wv >> 1) * 32;
  const int fr   = lane & 15;
  const int kg   = lane >> 4;
  const int cA   = fr & 7;

  const unsigned short* Ag = act + ((size_t)e * 640 + m0) * 3072;
  const float* Bg = W2 + (size_t)e * 3072 * 768 + n0;

  const int srow = wv * 8 + (lane >> 3);
  const int scol = (((lane & 7) ^ ((lane >> 3) & 7)) * 8);
  unsigned short* ldsA = As + wv * 512;

  f32x4 acc[4][2];
  f32x4 zero4 = {0.f, 0.f, 0.f, 0.f};
  #pragma unroll
  for (int m = 0; m < 4; m++)
    #pragma unroll
    for (int n = 0; n < 2; n++) acc[m][n] = zero4;

  uint4 pb[4];
  if (tid < 128) stageB8_load<16>(Bg, 768, pb, tid);

  for (int kt = 0; kt < 3072; kt += 64){
    if (kt) __syncthreads();
    if (tid < 128) stageB8_write<16>(pb, Bs, tid);
    #pragma unroll
    for (int c = 0; c < 4; c++){
      int r = c * 32 + srow;
      gload16(Ag + (size_t)r * 3072 + kt + scol, ldsA + c * 2048);
    }
    __syncthreads();
    if (kt + 64 < 3072 && tid < 128)
      stageB8_load<16>(Bg + (size_t)(kt + 64) * 768, 768, pb, tid);
    #pragma unroll
    for (int kk = 0; kk < 2; kk++){
      short8v af[4], bf[2];
      #pragma unroll
      for (int m = 0; m < 4; m++)
        af[m] = *(const short8v*)(As + (wr + m * 16 + fr) * 64 + (((kk * 4 + kg) ^ cA) * 8));
      #pragma unroll
      for (int n = 0; n < 2; n++){
        int R = wc + n * 16 + fr;
        int cx = (((kk * 4 + kg) ^ ((R >> 3) & 7)) * 8);
        bf[n] = *(const short8v*)(Bs + R * BLDP + cx);
      }
      #pragma unroll
      for (int m = 0; m < 4; m++)
        #pragma unroll
        for (int n = 0; n < 2; n++)
          acc[m][n] = __builtin_amdgcn_mfma_f32_16x16x32_bf16(af[m], bf[n], acc[m][n], 0, 0, 0);
    }
  }
  float b2v[2];
  #pragma unroll
  for (int n = 0; n < 2; n++) b2v[n] = b2[(size_t)e * 768 + n0 + wc + n * 16 + fr];
  #pragma unroll
  for (int m = 0; m < 4; m++){
    #pragma unroll
    for (int r = 0; r < 4; r++){
      int row = m0 + wr + m * 16 + kg * 4 + r;
      #pragma unroll
      for (int n = 0; n < 2; n++){
        int col = n0 + wc + n * 16 + fr;
        y[((size_t)e * 640 + row) * 768 + col] = acc[m][n][r] + b2v[n];
      }
    }
  }
}

// ---------------- combine-weight scatter: y[e][c] * cw -> out[token] ----------------
__global__ __launch_bounds__(192) void combine_scatter_kernel(
    const float* __restrict__ y, const int* __restrict__ expert_tok,
    const float* __restrict__ cw, float* __restrict__ out)
{
  int ec = blockIdx.x;
  int token = expert_tok[ec];
  if (token < 0) return;
  float w = cw[ec];
  int t4 = threadIdx.x * 4;
  float4 v = *(const float4*)(y + (size_t)ec * 768 + t4);
  v.x *= w; v.y *= w; v.z *= w; v.w *= w;
  *(float4*)(out + (size_t)token * 768 + t4) = v;
}

// ---------------- dense fallback for dropped tokens only ----------------
__global__ __launch_bounds__(256) void fallback_kernel(
    const float* __restrict__ x,
    const float* __restrict__ W1f, const float* __restrict__ b1f,
    const float* __restrict__ W2f, const float* __restrict__ b2f,
    const int* __restrict__ dropped, float* __restrict__ out)
{
  int t = blockIdx.x;
  if (dropped[t] == 0) return;
  __shared__ float xs[768];
  __shared__ float hs[6144];
  int tid = threadIdx.x;
  for (int d = tid; d < 768; d += 256) xs[d] = x[(size_t)t * 768 + d];
  __syncthreads();
  for (int j = tid; j < 6144; j += 256){
    float a = b1f[j];
    for (int d = 0; d < 768; d++) a += xs[d] * W1f[(size_t)d * 6144 + j];
    hs[j] = a;
  }
  __syncthreads();
  for (int j = tid; j < 3072; j += 256){
    float hg = hs[j], hu = hs[j + 3072];
    hs[j] = (hg / (1.0f + __expf(-hg))) * hu;
  }
  __syncthreads();
  for (int d = tid; d < 768; d += 256){
    float a = b2f[d];
    for (int h = 0; h < 3072; h++) a += hs[h] * W2f[(size_t)h * 768 + d];
    out[(size_t)t * 768 + d] = a;   // FALLBACK_W = 1.0
  }
}

extern "C" void kernel_launch(void* const* d_in, const int* in_sizes, int n_in,
                              void* d_out, int out_size, void* d_ws, size_t ws_size,
                              hipStream_t stream) {
  const float* x   = (const float*)d_in[0];
  const float* Wr  = (const float*)d_in[1];
  const float* W1  = (const float*)d_in[2];
  const float* b1  = (const float*)d_in[3];
  const float* W2  = (const float*)d_in[4];
  const float* b2  = (const float*)d_in[5];
  const float* W1f = (const float*)d_in[6];
  const float* b1f = (const float*)d_in[7];
  const float* W2f = (const float*)d_in[8];
  const float* b2f = (const float*)d_in[9];
  float* out = (float*)d_out;

  char* ws = (char*)d_ws;
  int*            expert_tok = (int*)  (ws + 0);          // 16*640*4 = 40960
  float*          cw         = (float*)(ws + 40960);
  int*            eid        = (int*)  (ws + 81920);
  float*          gate       = (float*)(ws + 114688);
  int*            drop       = (int*)  (ws + 147456);
  unsigned short* xa         = (unsigned short*)(ws + 180224);     // 16*640*768*2  = 15728640
  unsigned short* act        = (unsigned short*)(ws + 15908864);   // 16*640*3072*2 = 62914560
  float*          y          = (float*)(ws + 78823424);            // 16*640*768*4  = 31457280
  // total ws use: ~110 MB

  init_tok_kernel<<<40, 256, 0, stream>>>(expert_tok);
  router_kernel<<<2048, 256, 0, stream>>>(x, Wr, eid, gate);
  scan_route_kernel<<<1, 256, 0, stream>>>(eid, gate, expert_tok, cw, drop);
  gather_x_kernel<<<16 * CAP, 192, 0, stream>>>(x, expert_tok, xa);
  gemm1_swiglu_kernel<<<3840, 256, 0, stream>>>(xa, W1, b1, act);
  gemm2_kernel<<<960, 256, 0, stream>>>(act, W2, b2, y);
  combine_scatter_kernel<<<16 * CAP, 192, 0, stream>>>(y, expert_tok, cw, out);
  fallback_kernel<<<NTOK, 256, 0, stream>>>(x, W1f, b1f, W2f, b2f, drop, out);
}

// Round 11
// 358.926 us; speedup vs baseline: 1.0945x; 1.0945x over previous
//
#include <hip/hip_runtime.h>
#include <cstdint>
#include <cstddef>

#define NTOK 8192
#define DMODEL 768
#define NEXP 16
#define HDIM 3072
#define CAP 640
#define BLDP 72   // LDS row stride (elems) for B tiles; 144B = 9*16B

typedef __attribute__((ext_vector_type(8))) short short8v;
typedef __attribute__((ext_vector_type(4))) float f32x4;

static __device__ __forceinline__ unsigned short f2bf(float f){
  union { float f; unsigned int u; } v; v.f = f;
  unsigned int u = v.u;
  unsigned int r = (u + 0x7FFFu + ((u >> 16) & 1u)) >> 16;
  return (unsigned short)r;
}
// round-half-up pack: 0.5-ulp bound like RTNE (differs only on exact ties),
// ~3 VALU per 2 elems. Plain C = sinkable. HW-validated R10 (absmax unchanged).
static __device__ __forceinline__ unsigned int pk2b(float a, float b){
  unsigned int ua = __builtin_bit_cast(unsigned int, a) + 0x8000u;
  unsigned int ub = __builtin_bit_cast(unsigned int, b) + 0x8000u;
  return (ua >> 16) | (ub & 0xFFFF0000u);
}

// async global(16B per lane) -> LDS (wave-uniform base + lane*16)
static __device__ __forceinline__ void gload16(const unsigned short* g, unsigned short* l){
  __builtin_amdgcn_global_load_lds(
      (const __attribute__((address_space(1))) unsigned int*)g,
      (__attribute__((address_space(3))) unsigned int*)l, 16, 0, 0);
}

// ---------------- init expert_tok = -1 ----------------
__global__ void init_tok_kernel(int* __restrict__ expert_tok){
  int i = blockIdx.x * 256 + threadIdx.x;   // 40*256 = 10240 exact
  expert_tok[i] = -1;
}

// ---------------- router: logits, softmax-gate, argmax ----------------
__global__ __launch_bounds__(256) void router_kernel(
    const float* __restrict__ x, const float* __restrict__ Wr,
    int* __restrict__ eid, float* __restrict__ gate)
{
  int t = blockIdx.x * 4 + (threadIdx.x >> 6);
  int lane = threadIdx.x & 63;
  const float* xr = x + (size_t)t * DMODEL;
  float acc[16];
  #pragma unroll
  for (int e = 0; e < 16; e++) acc[e] = 0.f;
  #pragma unroll
  for (int i = 0; i < 12; i++){
    float xv = xr[lane + i * 64];
    const float* wrow = Wr + (size_t)(lane + i * 64) * 16;
    #pragma unroll
    for (int e = 0; e < 16; e++) acc[e] += xv * wrow[e];
  }
  #pragma unroll
  for (int e = 0; e < 16; e++){
    float v = acc[e];
    #pragma unroll
    for (int off = 32; off >= 1; off >>= 1) v += __shfl_xor(v, off, 64);
    acc[e] = v;
  }
  if (lane == 0){
    float mx = acc[0]; int bi = 0;
    #pragma unroll
    for (int e = 1; e < 16; e++) if (acc[e] > mx){ mx = acc[e]; bi = e; }
    float s = 0.f;
    #pragma unroll
    for (int e = 0; e < 16; e++) s += __expf(acc[e] - mx);
    eid[t] = bi;
    gate[t] = 1.0f / s;   // softmax value at the argmax
  }
}

// ---------------- order-preserving slot scan (1 block) ----------------
__global__ __launch_bounds__(256) void scan_route_kernel(
    const int* __restrict__ eid, const float* __restrict__ gate,
    int* __restrict__ expert_tok, float* __restrict__ cw, int* __restrict__ dropped)
{
  __shared__ int hist[256][16];
  int t = threadIdx.x;
  #pragma unroll
  for (int e = 0; e < 16; e++) hist[t][e] = 0;
  __syncthreads();
  for (int i = 0; i < 32; i++){
    int tok = t * 32 + i;
    hist[t][eid[tok]]++;
  }
  __syncthreads();
  if (t < 16){
    int run = 0;
    for (int i = 0; i < 256; i++){ int c = hist[i][t]; hist[i][t] = run; run += c; }
  }
  __syncthreads();
  for (int i = 0; i < 32; i++){
    int tok = t * 32 + i;
    int e = eid[tok];
    int slot = hist[t][e]++;
    if (slot < CAP){
      expert_tok[e * CAP + slot] = tok;
      cw[e * CAP + slot] = gate[tok];
      dropped[tok] = 0;
    } else {
      dropped[tok] = 1;
    }
  }
}

// ---------------- gather x rows -> bf16 [E][C][D] ----------------
__global__ __launch_bounds__(192) void gather_x_kernel(
    const float* __restrict__ x, const int* __restrict__ expert_tok,
    unsigned short* __restrict__ xa)
{
  int ec = blockIdx.x;
  int token = expert_tok[ec];
  int t4 = threadIdx.x * 4;
  ushort4 o;
  if (token >= 0){
    const float4 v = *(const float4*)(x + (size_t)token * DMODEL + t4);
    o.x = f2bf(v.x); o.y = f2bf(v.y); o.z = f2bf(v.z); o.w = f2bf(v.w);
  } else {
    o.x = 0; o.y = 0; o.z = 0; o.w = 0;
  }
  *(ushort4*)(xa + (size_t)ec * DMODEL + t4) = o;
}

// ---- B staging, 64x64 f32 tile, 256 threads: thread (nq=tid&15, kq=tid>>4)
// covers cols nq*4..+4, rows kq*4..+4. Writes b64 at chunk (kq>>1)^((R>>3)&7)
// (2-way = free); b128 reads conflict-free with cx = (kk*4+kg)^((R>>3)&7).
static __device__ __forceinline__ void stage64_load(
    const float* __restrict__ g, int ldg, uint2* p, int nq, int kq)
{
  const float* s = g + (size_t)(kq * 4) * ldg + (size_t)nq * 4;
  float4 r0 = *(const float4*)(s);
  float4 r1 = *(const float4*)(s + ldg);
  float4 r2 = *(const float4*)(s + 2 * ldg);
  float4 r3 = *(const float4*)(s + 3 * ldg);
  p[0].x = pk2b(r0.x, r1.x); p[0].y = pk2b(r2.x, r3.x);
  p[1].x = pk2b(r0.y, r1.y); p[1].y = pk2b(r2.y, r3.y);
  p[2].x = pk2b(r0.z, r1.z); p[2].y = pk2b(r2.z, r3.z);
  p[3].x = pk2b(r0.w, r1.w); p[3].y = pk2b(r2.w, r3.w);
}
static __device__ __forceinline__ void stage64_write(
    const uint2* p, unsigned short* __restrict__ lds, int nq, int kq)
{
  #pragma unroll
  for (int j = 0; j < 4; j++){
    int R = nq * 4 + j;
    int c8 = (kq >> 1) ^ ((R >> 3) & 7);
    *(uint2*)(lds + R * BLDP + c8 * 8 + (kq & 1) * 4) = p[j];
  }
}

// ---- B staging for gemm2 (128 stager threads): cols nq*4..+4, rows kq*8..+8 ----
template<int NQ>
static __device__ __forceinline__ void stageB8_load(
    const float* __restrict__ g, int ldg, uint4* p, int tid)
{
  const int nq = tid % NQ, kq = tid / NQ;
  const float* s = g + (size_t)(kq * 8) * ldg + (size_t)nq * 4;
  float4 r[8];
  #pragma unroll
  for (int i = 0; i < 8; i++) r[i] = *(const float4*)(s + (size_t)i * ldg);
  #pragma unroll
  for (int j = 0; j < 4; j++){
    p[j].x = pk2b(((const float*)&r[0])[j], ((const float*)&r[1])[j]);
    p[j].y = pk2b(((const float*)&r[2])[j], ((const float*)&r[3])[j]);
    p[j].z = pk2b(((const float*)&r[4])[j], ((const float*)&r[5])[j]);
    p[j].w = pk2b(((const float*)&r[6])[j], ((const float*)&r[7])[j]);
  }
}
template<int NQ>
static __device__ __forceinline__ void stageB8_write(
    const uint4* p, unsigned short* __restrict__ lds, int tid)
{
  const int nq = tid % NQ, kq = tid / NQ;
  #pragma unroll
  for (int j = 0; j < 4; j++){
    int R = nq * 4 + j;
    int c = kq ^ ((R >> 3) & 7);
    *(uint4*)(lds + R * BLDP + c * 8) = p[j];
  }
}

// ---------------- GEMM1: xa @ W1 (fused cvt) + swiglu -> act bf16 ----------------
// Narrow-n: 256 thr, block = 128m x (64 g + 64 u), LDS 34.4KB, launch_bounds(256,3)
// (R9 config — (256,4) regressed: L2 thrash, FETCH+WRITE amplification, R10).
__global__ __launch_bounds__(256, 3) void gemm1_swiglu_kernel(
    const unsigned short* __restrict__ xa,
    const float* __restrict__ W1,
    const float* __restrict__ b1,
    unsigned short* __restrict__ act)
{
  __shared__ unsigned short As [128 * 64];     // 16 KB
  __shared__ unsigned short Bgs[64 * BLDP];    // 9.2 KB
  __shared__ unsigned short Bus[64 * BLDP];    // 9.2 KB
  const int b = blockIdx.x;
  const int w = (b & 7) * 480 + (b >> 3);      // bijective XCD chunking (3840 = 8*480)
  const int mb = w % 5;
  const int nb = (w / 5) % 48;
  const int e  = w / 240;
  const int m0 = mb * 128;
  const int n0 = nb * 64;
  const int tid  = threadIdx.x;
  const int lane = tid & 63;
  const int wv   = tid >> 6;          // 0..3
  const int wr   = (wv >> 1) * 64;    // m-half
  const int wc   = (wv & 1) * 32;     // n-half of 64
  const int fr   = lane & 15;
  const int kg   = lane >> 4;
  const int cA   = fr & 7;            // A-read chunk XOR
  const int nq   = tid & 15;          // B-stage col group (16*4 = 64)
  const int kq   = tid >> 4;          // B-stage k group  (16*4 = 64)

  const unsigned short* Ag = xa + ((size_t)e * 640 + m0) * 768;
  const float* Bg = W1 + (size_t)e * 768 * 6144 + n0;
  const float* Bu = Bg + 3072;

  // A staging: linear LDS dest; global source chunk-XOR pre-swizzled (G21)
  const int srow = wv * 8 + (lane >> 3);
  const int scol = (((lane & 7) ^ ((lane >> 3) & 7)) * 8);
  unsigned short* ldsA = As + wv * 512;

  f32x4 accg[4][2], accu[4][2];
  f32x4 zero4 = {0.f, 0.f, 0.f, 0.f};
  #pragma unroll
  for (int m = 0; m < 4; m++)
    #pragma unroll
    for (int n = 0; n < 2; n++){ accg[m][n] = zero4; accu[m][n] = zero4; }

  uint2 pg[4], pu[4];
  stage64_load(Bg, 6144, pg, nq, kq);
  stage64_load(Bu, 6144, pu, nq, kq);

  for (int kt = 0; kt < 768; kt += 64){
    if (kt) __syncthreads();           // previous compute's LDS reads done
    stage64_write(pg, Bgs, nq, kq);
    stage64_write(pu, Bus, nq, kq);
    #pragma unroll
    for (int c = 0; c < 4; c++){
      int r = c * 32 + srow;
      gload16(Ag + (size_t)r * 768 + kt + scol, ldsA + c * 2048);
    }
    __syncthreads();                   // drains vmcnt (A) + lgkm (B writes)
    if (kt + 64 < 768){                // prefetch next B during MFMA phase
      stage64_load(Bg + (size_t)(kt + 64) * 6144, 6144, pg, nq, kq);
      stage64_load(Bu + (size_t)(kt + 64) * 6144, 6144, pu, nq, kq);
    }
    #pragma unroll
    for (int kk = 0; kk < 2; kk++){
      short8v af[4], bgf[2], buf[2];
      #pragma unroll
      for (int m = 0; m < 4; m++)
        af[m] = *(const short8v*)(As + (wr + m * 16 + fr) * 64 + (((kk * 4 + kg) ^ cA) * 8));
      #pragma unroll
      for (int n = 0; n < 2; n++){
        int R = wc + n * 16 + fr;
        int cx = (((kk * 4 + kg) ^ ((R >> 3) & 7)) * 8);
        bgf[n] = *(const short8v*)(Bgs + R * BLDP + cx);
        buf[n] = *(const short8v*)(Bus + R * BLDP + cx);
      }
      #pragma unroll
      for (int m = 0; m < 4; m++)
        #pragma unroll
        for (int n = 0; n < 2; n++){
          accg[m][n] = __builtin_amdgcn_mfma_f32_16x16x32_bf16(af[m], bgf[n], accg[m][n], 0, 0, 0);
          accu[m][n] = __builtin_amdgcn_mfma_f32_16x16x32_bf16(af[m], buf[n], accu[m][n], 0, 0, 0);
        }
    }
  }
  // epilogue: (+bias) -> silu(g)*u -> bf16 act
  #pragma unroll
  for (int n = 0; n < 2; n++){
    int col = n0 + wc + n * 16 + fr;
    float b_g = b1[(size_t)e * 6144 + col];
    float b_u = b1[(size_t)e * 6144 + 3072 + col];
    #pragma unroll
    for (int m = 0; m < 4; m++){
      #pragma unroll
      for (int r = 0; r < 4; r++){
        int row = m0 + wr + m * 16 + kg * 4 + r;
        float hg = accg[m][n][r] + b_g;
        float hu = accu[m][n][r] + b_u;
        float s = (hg / (1.0f + __expf(-hg))) * hu;
        act[((size_t)e * 640 + row) * 3072 + col] = f2bf(s);
      }
    }
  }
}

// ---------------- GEMM2: act @ W2 (fused cvt) + b2 -> y f32 ----------
__global__ __launch_bounds__(256, 3) void gemm2_kernel(
    const unsigned short* __restrict__ act,
    const float* __restrict__ W2,
    const float* __restrict__ b2,
    float* __restrict__ y)                   // [E][640][768]
{
  __shared__ unsigned short As[128 * 64];
  __shared__ unsigned short Bs[64 * BLDP];
  const int b = blockIdx.x;
  const int w = (b & 7) * 120 + (b >> 3);
  const int mb = w % 5;
  const int nb = (w / 5) % 12;
  const int e  = w / 60;
  const int m0 = mb * 128;
  const int n0 = nb * 64;
  const int tid  = threadIdx.x;
  const int lane = tid & 63;
  const int wv   = tid >> 6;
  const int wr   = (wv & 1) * 64;
  const int wc   = (wv >> 1) * 32;
  const int fr   = lane & 15;
  const int kg   = lane >> 4;
  const int cA   = fr & 7;

  const unsigned short* Ag = act + ((size_t)e * 640 + m0) * 3072;
  const float* Bg = W2 + (size_t)e * 3072 * 768 + n0;

  const int srow = wv * 8 + (lane >> 3);
  const int scol = (((lane & 7) ^ ((lane >> 3) & 7)) * 8);
  unsigned short* ldsA = As + wv * 512;

  f32x4 acc[4][2];
  f32x4 zero4 = {0.f, 0.f, 0.f, 0.f};
  #pragma unroll
  for (int m = 0; m < 4; m++)
    #pragma unroll
    for (int n = 0; n < 2; n++) acc[m][n] = zero4;

  uint4 pb[4];
  if (tid < 128) stageB8_load<16>(Bg, 768, pb, tid);

  for (int kt = 0; kt < 3072; kt += 64){
    if (kt) __syncthreads();
    if (tid < 128) stageB8_write<16>(pb, Bs, tid);
    #pragma unroll
    for (int c = 0; c < 4; c++){
      int r = c * 32 + srow;
      gload16(Ag + (size_t)r * 3072 + kt + scol, ldsA + c * 2048);
    }
    __syncthreads();
    if (kt + 64 < 3072 && tid < 128)
      stageB8_load<16>(Bg + (size_t)(kt + 64) * 768, 768, pb, tid);
    #pragma unroll
    for (int kk = 0; kk < 2; kk++){
      short8v af[4], bf[2];
      #pragma unroll
      for (int m = 0; m < 4; m++)
        af[m] = *(const short8v*)(As + (wr + m * 16 + fr) * 64 + (((kk * 4 + kg) ^ cA) * 8));
      #pragma unroll
      for (int n = 0; n < 2; n++){
        int R = wc + n * 16 + fr;
        int cx = (((kk * 4 + kg) ^ ((R >> 3) & 7)) * 8);
        bf[n] = *(const short8v*)(Bs + R * BLDP + cx);
      }
      #pragma unroll
      for (int m = 0; m < 4; m++)
        #pragma unroll
        for (int n = 0; n < 2; n++)
          acc[m][n] = __builtin_amdgcn_mfma_f32_16x16x32_bf16(af[m], bf[n], acc[m][n], 0, 0, 0);
    }
  }
  float b2v[2];
  #pragma unroll
  for (int n = 0; n < 2; n++) b2v[n] = b2[(size_t)e * 768 + n0 + wc + n * 16 + fr];
  #pragma unroll
  for (int m = 0; m < 4; m++){
    #pragma unroll
    for (int r = 0; r < 4; r++){
      int row = m0 + wr + m * 16 + kg * 4 + r;
      #pragma unroll
      for (int n = 0; n < 2; n++){
        int col = n0 + wc + n * 16 + fr;
        y[((size_t)e * 640 + row) * 768 + col] = acc[m][n][r] + b2v[n];
      }
    }
  }
}

// ---------------- combine-weight scatter: y[e][c] * cw -> out[token] ----------------
__global__ __launch_bounds__(192) void combine_scatter_kernel(
    const float* __restrict__ y, const int* __restrict__ expert_tok,
    const float* __restrict__ cw, float* __restrict__ out)
{
  int ec = blockIdx.x;
  int token = expert_tok[ec];
  if (token < 0) return;
  float w = cw[ec];
  int t4 = threadIdx.x * 4;
  float4 v = *(const float4*)(y + (size_t)ec * 768 + t4);
  v.x *= w; v.y *= w; v.z *= w; v.w *= w;
  *(float4*)(out + (size_t)token * 768 + t4) = v;
}

// ---------------- dense fallback for dropped tokens only ----------------
__global__ __launch_bounds__(256) void fallback_kernel(
    const float* __restrict__ x,
    const float* __restrict__ W1f, const float* __restrict__ b1f,
    const float* __restrict__ W2f, const float* __restrict__ b2f,
    const int* __restrict__ dropped, float* __restrict__ out)
{
  int t = blockIdx.x;
  if (dropped[t] == 0) return;
  __shared__ float xs[768];
  __shared__ float hs[6144];
  int tid = threadIdx.x;
  for (int d = tid; d < 768; d += 256) xs[d] = x[(size_t)t * 768 + d];
  __syncthreads();
  for (int j = tid; j < 6144; j += 256){
    float a = b1f[j];
    for (int d = 0; d < 768; d++) a += xs[d] * W1f[(size_t)d * 6144 + j];
    hs[j] = a;
  }
  __syncthreads();
  for (int j = tid; j < 3072; j += 256){
    float hg = hs[j], hu = hs[j + 3072];
    hs[j] = (hg / (1.0f + __expf(-hg))) * hu;
  }
  __syncthreads();
  for (int d = tid; d < 768; d += 256){
    float a = b2f[d];
    for (int h = 0; h < 3072; h++) a += hs[h] * W2f[(size_t)h * 768 + d];
    out[(size_t)t * 768 + d] = a;   // FALLBACK_W = 1.0
  }
}

extern "C" void kernel_launch(void* const* d_in, const int* in_sizes, int n_in,
                              void* d_out, int out_size, void* d_ws, size_t ws_size,
                              hipStream_t stream) {
  const float* x   = (const float*)d_in[0];
  const float* Wr  = (const float*)d_in[1];
  const float* W1  = (const float*)d_in[2];
  const float* b1  = (const float*)d_in[3];
  const float* W2  = (const float*)d_in[4];
  const float* b2  = (const float*)d_in[5];
  const float* W1f = (const float*)d_in[6];
  const float* b1f = (const float*)d_in[7];
  const float* W2f = (const float*)d_in[8];
  const float* b2f = (const float*)d_in[9];
  float* out = (float*)d_out;

  char* ws = (char*)d_ws;
  int*            expert_tok = (int*)  (ws + 0);          // 16*640*4 = 40960
  float*          cw         = (float*)(ws + 40960);
  int*            eid        = (int*)  (ws + 81920);
  float*          gate       = (float*)(ws + 114688);
  int*            drop       = (int*)  (ws + 147456);
  unsigned short* xa         = (unsigned short*)(ws + 180224);     // 16*640*768*2  = 15728640
  unsigned short* act        = (unsigned short*)(ws + 15908864);   // 16*640*3072*2 = 62914560
  float*          y          = (float*)(ws + 78823424);            // 16*640*768*4  = 31457280
  // total ws use: ~110 MB

  init_tok_kernel<<<40, 256, 0, stream>>>(expert_tok);
  router_kernel<<<2048, 256, 0, stream>>>(x, Wr, eid, gate);
  scan_route_kernel<<<1, 256, 0, stream>>>(eid, gate, expert_tok, cw, drop);
  gather_x_kernel<<<16 * CAP, 192, 0, stream>>>(x, expert_tok, xa);
  gemm1_swiglu_kernel<<<3840, 256, 0, stream>>>(xa, W1, b1, act);
  gemm2_kernel<<<960, 256, 0, stream>>>(act, W2, b2, y);
  combine_scatter_kernel<<<16 * CAP, 192, 0, stream>>>(y, expert_tok, cw, out);
  fallback_kernel<<<NTOK, 256, 0, stream>>>(x, W1f, b1f, W2f, b2f, drop, out);
}

// Round 12
// 352.169 us; speedup vs baseline: 1.1155x; 1.0192x over previous
//
#include <hip/hip_runtime.h>
#include <cstdint>
#include <cstddef>

#define NTOK 8192
#define DMODEL 768
#define NEXP 16
#define HDIM 3072
#define CAP 640
#define BLDP 72   // LDS row stride (elems) for B tiles; 144B = 9*16B

typedef __attribute__((ext_vector_type(8))) short short8v;
typedef __attribute__((ext_vector_type(4))) float f32x4;

static __device__ __forceinline__ unsigned short f2bf(float f){
  union { float f; unsigned int u; } v; v.f = f;
  unsigned int u = v.u;
  unsigned int r = (u + 0x7FFFu + ((u >> 16) & 1u)) >> 16;
  return (unsigned short)r;
}
// round-half-up pack: 0.5-ulp bound like RTNE (differs only on exact ties),
// ~3 VALU per 2 elems. Plain C = sinkable. HW-validated R10 (absmax unchanged).
static __device__ __forceinline__ unsigned int pk2b(float a, float b){
  unsigned int ua = __builtin_bit_cast(unsigned int, a) + 0x8000u;
  unsigned int ub = __builtin_bit_cast(unsigned int, b) + 0x8000u;
  return (ua >> 16) | (ub & 0xFFFF0000u);
}

// async global(16B per lane) -> LDS (wave-uniform base + lane*16)
static __device__ __forceinline__ void gload16(const unsigned short* g, unsigned short* l){
  __builtin_amdgcn_global_load_lds(
      (const __attribute__((address_space(1))) unsigned int*)g,
      (__attribute__((address_space(3))) unsigned int*)l, 16, 0, 0);
}

// ---------------- init expert_tok = -1 ----------------
__global__ void init_tok_kernel(int* __restrict__ expert_tok){
  int i = blockIdx.x * 256 + threadIdx.x;   // 40*256 = 10240 exact
  expert_tok[i] = -1;
}

// ---------------- router: logits, softmax-gate, argmax ----------------
__global__ __launch_bounds__(256) void router_kernel(
    const float* __restrict__ x, const float* __restrict__ Wr,
    int* __restrict__ eid, float* __restrict__ gate)
{
  int t = blockIdx.x * 4 + (threadIdx.x >> 6);
  int lane = threadIdx.x & 63;
  const float* xr = x + (size_t)t * DMODEL;
  float acc[16];
  #pragma unroll
  for (int e = 0; e < 16; e++) acc[e] = 0.f;
  #pragma unroll
  for (int i = 0; i < 12; i++){
    float xv = xr[lane + i * 64];
    const float* wrow = Wr + (size_t)(lane + i * 64) * 16;
    #pragma unroll
    for (int e = 0; e < 16; e++) acc[e] += xv * wrow[e];
  }
  #pragma unroll
  for (int e = 0; e < 16; e++){
    float v = acc[e];
    #pragma unroll
    for (int off = 32; off >= 1; off >>= 1) v += __shfl_xor(v, off, 64);
    acc[e] = v;
  }
  if (lane == 0){
    float mx = acc[0]; int bi = 0;
    #pragma unroll
    for (int e = 1; e < 16; e++) if (acc[e] > mx){ mx = acc[e]; bi = e; }
    float s = 0.f;
    #pragma unroll
    for (int e = 0; e < 16; e++) s += __expf(acc[e] - mx);
    eid[t] = bi;
    gate[t] = 1.0f / s;   // softmax value at the argmax
  }
}

// ---------------- order-preserving slot scan (1 block, parallel prefix) --------
__global__ __launch_bounds__(256) void scan_route_kernel(
    const int* __restrict__ eid, const float* __restrict__ gate,
    int* __restrict__ expert_tok, float* __restrict__ cw, int* __restrict__ dropped)
{
  __shared__ int hist[256][17];   // pad 17: phase-1 RMW conflict-free-ish
  __shared__ int wtot[4][16];
  int t = threadIdx.x;
  int lane = t & 63, wv = t >> 6;
  #pragma unroll
  for (int e = 0; e < 16; e++) hist[t][e] = 0;
  __syncthreads();
  for (int i = 0; i < 32; i++){
    int tok = t * 32 + i;
    hist[t][eid[tok]]++;
  }
  __syncthreads();
  // exclusive scan over t (global token order) per expert: wave shfl-scan + wave totals
  int ex[16];
  #pragma unroll
  for (int e = 0; e < 16; e++){
    int v = hist[t][e];
    int s = v;
    #pragma unroll
    for (int d = 1; d < 64; d <<= 1){
      int o = __shfl_up(s, d, 64);
      if (lane >= d) s += o;
    }
    ex[e] = s - v;
    if (lane == 63) wtot[wv][e] = s;
  }
  __syncthreads();
  if (t < 16){
    int run = 0;
    #pragma unroll
    for (int w = 0; w < 4; w++){ int c = wtot[w][t]; wtot[w][t] = run; run += c; }
  }
  __syncthreads();
  #pragma unroll
  for (int e = 0; e < 16; e++) hist[t][e] = ex[e] + wtot[wv][e];
  __syncthreads();
  for (int i = 0; i < 32; i++){
    int tok = t * 32 + i;
    int e = eid[tok];
    int slot = hist[t][e]++;
    if (slot < CAP){
      expert_tok[e * CAP + slot] = tok;
      cw[e * CAP + slot] = gate[tok];
      dropped[tok] = 0;
    } else {
      dropped[tok] = 1;
    }
  }
}

// ---------------- gather x rows -> bf16 [E][C][D] ----------------
__global__ __launch_bounds__(192) void gather_x_kernel(
    const float* __restrict__ x, const int* __restrict__ expert_tok,
    unsigned short* __restrict__ xa)
{
  int ec = blockIdx.x;
  int token = expert_tok[ec];
  int t4 = threadIdx.x * 4;
  ushort4 o;
  if (token >= 0){
    const float4 v = *(const float4*)(x + (size_t)token * DMODEL + t4);
    o.x = f2bf(v.x); o.y = f2bf(v.y); o.z = f2bf(v.z); o.w = f2bf(v.w);
  } else {
    o.x = 0; o.y = 0; o.z = 0; o.w = 0;
  }
  *(ushort4*)(xa + (size_t)ec * DMODEL + t4) = o;
}

// ---- B staging, 64x64 f32 tile, 256 threads: thread (nq=tid&15, kq=tid>>4)
// covers cols nq*4..+4, rows kq*4..+4. Writes b64 at chunk (kq>>1)^((R>>3)&7)
// (2-way = free); b128 reads conflict-free with cx = (kk*4+kg)^((R>>3)&7).
static __device__ __forceinline__ void stage64_load(
    const float* __restrict__ g, int ldg, uint2* p, int nq, int kq)
{
  const float* s = g + (size_t)(kq * 4) * ldg + (size_t)nq * 4;
  float4 r0 = *(const float4*)(s);
  float4 r1 = *(const float4*)(s + ldg);
  float4 r2 = *(const float4*)(s + 2 * ldg);
  float4 r3 = *(const float4*)(s + 3 * ldg);
  p[0].x = pk2b(r0.x, r1.x); p[0].y = pk2b(r2.x, r3.x);
  p[1].x = pk2b(r0.y, r1.y); p[1].y = pk2b(r2.y, r3.y);
  p[2].x = pk2b(r0.z, r1.z); p[2].y = pk2b(r2.z, r3.z);
  p[3].x = pk2b(r0.w, r1.w); p[3].y = pk2b(r2.w, r3.w);
}
static __device__ __forceinline__ void stage64_write(
    const uint2* p, unsigned short* __restrict__ lds, int nq, int kq)
{
  #pragma unroll
  for (int j = 0; j < 4; j++){
    int R = nq * 4 + j;
    int c8 = (kq >> 1) ^ ((R >> 3) & 7);
    *(uint2*)(lds + R * BLDP + c8 * 8 + (kq & 1) * 4) = p[j];
  }
}

// ---- B staging for gemm2 (128 stager threads): cols nq*4..+4, rows kq*8..+8 ----
template<int NQ>
static __device__ __forceinline__ void stageB8_load(
    const float* __restrict__ g, int ldg, uint4* p, int tid)
{
  const int nq = tid % NQ, kq = tid / NQ;
  const float* s = g + (size_t)(kq * 8) * ldg + (size_t)nq * 4;
  float4 r[8];
  #pragma unroll
  for (int i = 0; i < 8; i++) r[i] = *(const float4*)(s + (size_t)i * ldg);
  #pragma unroll
  for (int j = 0; j < 4; j++){
    p[j].x = pk2b(((const float*)&r[0])[j], ((const float*)&r[1])[j]);
    p[j].y = pk2b(((const float*)&r[2])[j], ((const float*)&r[3])[j]);
    p[j].z = pk2b(((const float*)&r[4])[j], ((const float*)&r[5])[j]);
    p[j].w = pk2b(((const float*)&r[6])[j], ((const float*)&r[7])[j]);
  }
}
template<int NQ>
static __device__ __forceinline__ void stageB8_write(
    const uint4* p, unsigned short* __restrict__ lds, int tid)
{
  const int nq = tid % NQ, kq = tid / NQ;
  #pragma unroll
  for (int j = 0; j < 4; j++){
    int R = nq * 4 + j;
    int c = kq ^ ((R >> 3) & 7);
    *(uint4*)(lds + R * BLDP + c * 8) = p[j];
  }
}

// ---------------- GEMM1: xa @ W1 (fused cvt) + swiglu -> act bf16 ----------------
// Narrow-n: 256 thr, block = 128m x (64 g + 64 u), LDS 34.4KB, launch_bounds(256,3)
// (R9/R11 config — UNCHANGED this round, serves as control).
__global__ __launch_bounds__(256, 3) void gemm1_swiglu_kernel(
    const unsigned short* __restrict__ xa,
    const float* __restrict__ W1,
    const float* __restrict__ b1,
    unsigned short* __restrict__ act)
{
  __shared__ unsigned short As [128 * 64];     // 16 KB
  __shared__ unsigned short Bgs[64 * BLDP];    // 9.2 KB
  __shared__ unsigned short Bus[64 * BLDP];    // 9.2 KB
  const int b = blockIdx.x;
  const int w = (b & 7) * 480 + (b >> 3);      // bijective XCD chunking (3840 = 8*480)
  const int mb = w % 5;
  const int nb = (w / 5) % 48;
  const int e  = w / 240;
  const int m0 = mb * 128;
  const int n0 = nb * 64;
  const int tid  = threadIdx.x;
  const int lane = tid & 63;
  const int wv   = tid >> 6;          // 0..3
  const int wr   = (wv >> 1) * 64;    // m-half
  const int wc   = (wv & 1) * 32;     // n-half of 64
  const int fr   = lane & 15;
  const int kg   = lane >> 4;
  const int cA   = fr & 7;            // A-read chunk XOR
  const int nq   = tid & 15;          // B-stage col group (16*4 = 64)
  const int kq   = tid >> 4;          // B-stage k group  (16*4 = 64)

  const unsigned short* Ag = xa + ((size_t)e * 640 + m0) * 768;
  const float* Bg = W1 + (size_t)e * 768 * 6144 + n0;
  const float* Bu = Bg + 3072;

  // A staging: linear LDS dest; global source chunk-XOR pre-swizzled (G21)
  const int srow = wv * 8 + (lane >> 3);
  const int scol = (((lane & 7) ^ ((lane >> 3) & 7)) * 8);
  unsigned short* ldsA = As + wv * 512;

  f32x4 accg[4][2], accu[4][2];
  f32x4 zero4 = {0.f, 0.f, 0.f, 0.f};
  #pragma unroll
  for (int m = 0; m < 4; m++)
    #pragma unroll
    for (int n = 0; n < 2; n++){ accg[m][n] = zero4; accu[m][n] = zero4; }

  uint2 pg[4], pu[4];
  stage64_load(Bg, 6144, pg, nq, kq);
  stage64_load(Bu, 6144, pu, nq, kq);

  for (int kt = 0; kt < 768; kt += 64){
    if (kt) __syncthreads();           // previous compute's LDS reads done
    stage64_write(pg, Bgs, nq, kq);
    stage64_write(pu, Bus, nq, kq);
    #pragma unroll
    for (int c = 0; c < 4; c++){
      int r = c * 32 + srow;
      gload16(Ag + (size_t)r * 768 + kt + scol, ldsA + c * 2048);
    }
    __syncthreads();                   // drains vmcnt (A) + lgkm (B writes)
    if (kt + 64 < 768){                // prefetch next B during MFMA phase
      stage64_load(Bg + (size_t)(kt + 64) * 6144, 6144, pg, nq, kq);
      stage64_load(Bu + (size_t)(kt + 64) * 6144, 6144, pu, nq, kq);
    }
    #pragma unroll
    for (int kk = 0; kk < 2; kk++){
      short8v af[4], bgf[2], buf[2];
      #pragma unroll
      for (int m = 0; m < 4; m++)
        af[m] = *(const short8v*)(As + (wr + m * 16 + fr) * 64 + (((kk * 4 + kg) ^ cA) * 8));
      #pragma unroll
      for (int n = 0; n < 2; n++){
        int R = wc + n * 16 + fr;
        int cx = (((kk * 4 + kg) ^ ((R >> 3) & 7)) * 8);
        bgf[n] = *(const short8v*)(Bgs + R * BLDP + cx);
        buf[n] = *(const short8v*)(Bus + R * BLDP + cx);
      }
      #pragma unroll
      for (int m = 0; m < 4; m++)
        #pragma unroll
        for (int n = 0; n < 2; n++){
          accg[m][n] = __builtin_amdgcn_mfma_f32_16x16x32_bf16(af[m], bgf[n], accg[m][n], 0, 0, 0);
          accu[m][n] = __builtin_amdgcn_mfma_f32_16x16x32_bf16(af[m], buf[n], accu[m][n], 0, 0, 0);
        }
    }
  }
  // epilogue: (+bias) -> silu(g)*u -> bf16 act
  #pragma unroll
  for (int n = 0; n < 2; n++){
    int col = n0 + wc + n * 16 + fr;
    float b_g = b1[(size_t)e * 6144 + col];
    float b_u = b1[(size_t)e * 6144 + 3072 + col];
    #pragma unroll
    for (int m = 0; m < 4; m++){
      #pragma unroll
      for (int r = 0; r < 4; r++){
        int row = m0 + wr + m * 16 + kg * 4 + r;
        float hg = accg[m][n][r] + b_g;
        float hu = accu[m][n][r] + b_u;
        float s = (hg / (1.0f + __expf(-hg))) * hu;
        act[((size_t)e * 640 + row) * 3072 + col] = f2bf(s);
      }
    }
  }
}

// ---------------- GEMM2: act @ W2 + b2, fused combine-weight scatter -> out ------
__global__ __launch_bounds__(256, 3) void gemm2_kernel(
    const unsigned short* __restrict__ act,
    const float* __restrict__ W2,
    const float* __restrict__ b2,
    const int* __restrict__ expert_tok,
    const float* __restrict__ cw,
    float* __restrict__ out)                 // [N][768]
{
  __shared__ unsigned short As[128 * 64];
  __shared__ unsigned short Bs[64 * BLDP];
  const int b = blockIdx.x;
  const int w = (b & 7) * 120 + (b >> 3);
  const int mb = w % 5;
  const int nb = (w / 5) % 12;
  const int e  = w / 60;
  const int m0 = mb * 128;
  const int n0 = nb * 64;
  const int tid  = threadIdx.x;
  const int lane = tid & 63;
  const int wv   = tid >> 6;
  const int wr   = (wv & 1) * 64;
  const int wc   = (wv >> 1) * 32;
  const int fr   = lane & 15;
  const int kg   = lane >> 4;
  const int cA   = fr & 7;

  const unsigned short* Ag = act + ((size_t)e * 640 + m0) * 3072;
  const float* Bg = W2 + (size_t)e * 3072 * 768 + n0;

  const int srow = wv * 8 + (lane >> 3);
  const int scol = (((lane & 7) ^ ((lane >> 3) & 7)) * 8);
  unsigned short* ldsA = As + wv * 512;

  f32x4 acc[4][2];
  f32x4 zero4 = {0.f, 0.f, 0.f, 0.f};
  #pragma unroll
  for (int m = 0; m < 4; m++)
    #pragma unroll
    for (int n = 0; n < 2; n++) acc[m][n] = zero4;

  uint4 pb[4];
  if (tid < 128) stageB8_load<16>(Bg, 768, pb, tid);

  for (int kt = 0; kt < 3072; kt += 64){
    if (kt) __syncthreads();
    if (tid < 128) stageB8_write<16>(pb, Bs, tid);
    #pragma unroll
    for (int c = 0; c < 4; c++){
      int r = c * 32 + srow;
      gload16(Ag + (size_t)r * 3072 + kt + scol, ldsA + c * 2048);
    }
    __syncthreads();
    if (kt + 64 < 3072 && tid < 128)
      stageB8_load<16>(Bg + (size_t)(kt + 64) * 768, 768, pb, tid);
    #pragma unroll
    for (int kk = 0; kk < 2; kk++){
      short8v af[4], bf[2];
      #pragma unroll
      for (int m = 0; m < 4; m++)
        af[m] = *(const short8v*)(As + (wr + m * 16 + fr) * 64 + (((kk * 4 + kg) ^ cA) * 8));
      #pragma unroll
      for (int n = 0; n < 2; n++){
        int R = wc + n * 16 + fr;
        int cx = (((kk * 4 + kg) ^ ((R >> 3) & 7)) * 8);
        bf[n] = *(const short8v*)(Bs + R * BLDP + cx);
      }
      #pragma unroll
      for (int m = 0; m < 4; m++)
        #pragma unroll
        for (int n = 0; n < 2; n++)
          acc[m][n] = __builtin_amdgcn_mfma_f32_16x16x32_bf16(af[m], bf[n], acc[m][n], 0, 0, 0);
    }
  }
  float b2v[2];
  #pragma unroll
  for (int n = 0; n < 2; n++) b2v[n] = b2[(size_t)e * 768 + n0 + wc + n * 16 + fr];
  #pragma unroll
  for (int m = 0; m < 4; m++){
    #pragma unroll
    for (int r = 0; r < 4; r++){
      int row = m0 + wr + m * 16 + kg * 4 + r;
      int token = expert_tok[e * CAP + row];
      if (token >= 0){
        float wgt = cw[e * CAP + row];
        #pragma unroll
        for (int n = 0; n < 2; n++){
          int col = n0 + wc + n * 16 + fr;
          out[(size_t)token * 768 + col] = (acc[m][n][r] + b2v[n]) * wgt;
        }
      }
    }
  }
}

// ---------------- dense fallback for dropped tokens only ----------------
__global__ __launch_bounds__(256) void fallback_kernel(
    const float* __restrict__ x,
    const float* __restrict__ W1f, const float* __restrict__ b1f,
    const float* __restrict__ W2f, const float* __restrict__ b2f,
    const int* __restrict__ dropped, float* __restrict__ out)
{
  int t = blockIdx.x;
  if (dropped[t] == 0) return;
  __shared__ float xs[768];
  __shared__ float hs[6144];
  int tid = threadIdx.x;
  for (int d = tid; d < 768; d += 256) xs[d] = x[(size_t)t * 768 + d];
  __syncthreads();
  for (int j = tid; j < 6144; j += 256){
    float a = b1f[j];
    for (int d = 0; d < 768; d++) a += xs[d] * W1f[(size_t)d * 6144 + j];
    hs[j] = a;
  }
  __syncthreads();
  for (int j = tid; j < 3072; j += 256){
    float hg = hs[j], hu = hs[j + 3072];
    hs[j] = (hg / (1.0f + __expf(-hg))) * hu;
  }
  __syncthreads();
  for (int d = tid; d < 768; d += 256){
    float a = b2f[d];
    for (int h = 0; h < 3072; h++) a += hs[h] * W2f[(size_t)h * 768 + d];
    out[(size_t)t * 768 + d] = a;   // FALLBACK_W = 1.0
  }
}

extern "C" void kernel_launch(void* const* d_in, const int* in_sizes, int n_in,
                              void* d_out, int out_size, void* d_ws, size_t ws_size,
                              hipStream_t stream) {
  const float* x   = (const float*)d_in[0];
  const float* Wr  = (const float*)d_in[1];
  const float* W1  = (const float*)d_in[2];
  const float* b1  = (const float*)d_in[3];
  const float* W2  = (const float*)d_in[4];
  const float* b2  = (const float*)d_in[5];
  const float* W1f = (const float*)d_in[6];
  const float* b1f = (const float*)d_in[7];
  const float* W2f = (const float*)d_in[8];
  const float* b2f = (const float*)d_in[9];
  float* out = (float*)d_out;

  char* ws = (char*)d_ws;
  int*            expert_tok = (int*)  (ws + 0);          // 16*640*4 = 40960
  float*          cw         = (float*)(ws + 40960);
  int*            eid        = (int*)  (ws + 81920);
  float*          gate       = (float*)(ws + 114688);
  int*            drop       = (int*)  (ws + 147456);
  unsigned short* xa         = (unsigned short*)(ws + 180224);     // 16*640*768*2  = 15728640
  unsigned short* act        = (unsigned short*)(ws + 15908864);   // 16*640*3072*2 = 62914560
  // total ws use: ~79 MB (y eliminated)

  init_tok_kernel<<<40, 256, 0, stream>>>(expert_tok);
  router_kernel<<<2048, 256, 0, stream>>>(x, Wr, eid, gate);
  scan_route_kernel<<<1, 256, 0, stream>>>(eid, gate, expert_tok, cw, drop);
  gather_x_kernel<<<16 * CAP, 192, 0, stream>>>(x, expert_tok, xa);
  gemm1_swiglu_kernel<<<3840, 256, 0, stream>>>(xa, W1, b1, act);
  gemm2_kernel<<<960, 256, 0, stream>>>(act, W2, b2, expert_tok, cw, out);
  fallback_kernel<<<NTOK, 256, 0, stream>>>(x, W1f, b1f, W2f, b2f, drop, out);
}

// Round 14
// 345.737 us; speedup vs baseline: 1.1363x; 1.0186x over previous
//
#include <hip/hip_runtime.h>
#include <cstdint>
#include <cstddef>

#define NTOK 8192
#define DMODEL 768
#define NEXP 16
#define HDIM 3072
#define CAP 640
#define BLDP 72   // LDS row stride (elems) for B tiles; 144B = 9*16B

typedef __attribute__((ext_vector_type(8))) short short8v;
typedef __attribute__((ext_vector_type(4))) float f32x4;

static __device__ __forceinline__ unsigned short f2bf(float f){
  union { float f; unsigned int u; } v; v.f = f;
  unsigned int u = v.u;
  unsigned int r = (u + 0x7FFFu + ((u >> 16) & 1u)) >> 16;
  return (unsigned short)r;
}
// round-half-up pack: 0.5-ulp like RTNE; ~3 VALU per 2 elems; sinkable (R10/R11-validated)
static __device__ __forceinline__ unsigned int pk2b(float a, float b){
  unsigned int ua = __builtin_bit_cast(unsigned int, a) + 0x8000u;
  unsigned int ub = __builtin_bit_cast(unsigned int, b) + 0x8000u;
  return (ua >> 16) | (ub & 0xFFFF0000u);
}

// async global(16B per lane) -> LDS (wave-uniform base + lane*16)
static __device__ __forceinline__ void gload16(const unsigned short* g, unsigned short* l){
  __builtin_amdgcn_global_load_lds(
      (const __attribute__((address_space(1))) unsigned int*)g,
      (__attribute__((address_space(3))) unsigned int*)l, 16, 0, 0);
}

// ---------------- init expert_tok = -1 ----------------
__global__ void init_tok_kernel(int* __restrict__ expert_tok){
  int i = blockIdx.x * 256 + threadIdx.x;   // 40*256 = 10240 exact
  expert_tok[i] = -1;
}

// ---------------- router: logits, softmax-gate, argmax ----------------
__global__ __launch_bounds__(256) void router_kernel(
    const float* __restrict__ x, const float* __restrict__ Wr,
    int* __restrict__ eid, float* __restrict__ gate)
{
  int t = blockIdx.x * 4 + (threadIdx.x >> 6);
  int lane = threadIdx.x & 63;
  const float* xr = x + (size_t)t * DMODEL;
  float acc[16];
  #pragma unroll
  for (int e = 0; e < 16; e++) acc[e] = 0.f;
  #pragma unroll
  for (int i = 0; i < 12; i++){
    float xv = xr[lane + i * 64];
    const float* wrow = Wr + (size_t)(lane + i * 64) * 16;
    #pragma unroll
    for (int e = 0; e < 16; e++) acc[e] += xv * wrow[e];
  }
  #pragma unroll
  for (int e = 0; e < 16; e++){
    float v = acc[e];
    #pragma unroll
    for (int off = 32; off >= 1; off >>= 1) v += __shfl_xor(v, off, 64);
    acc[e] = v;
  }
  if (lane == 0){
    float mx = acc[0]; int bi = 0;
    #pragma unroll
    for (int e = 1; e < 16; e++) if (acc[e] > mx){ mx = acc[e]; bi = e; }
    float s = 0.f;
    #pragma unroll
    for (int e = 0; e < 16; e++) s += __expf(acc[e] - mx);
    eid[t] = bi;
    gate[t] = 1.0f / s;   // softmax value at the argmax
  }
}

// ---------------- order-preserving slot scan (1 block, parallel prefix) --------
__global__ __launch_bounds__(256) void scan_route_kernel(
    const int* __restrict__ eid, const float* __restrict__ gate,
    int* __restrict__ expert_tok, float* __restrict__ cw, int* __restrict__ dropped)
{
  __shared__ int hist[256][17];
  __shared__ int wtot[4][16];
  int t = threadIdx.x;
  int lane = t & 63, wv = t >> 6;
  #pragma unroll
  for (int e = 0; e < 16; e++) hist[t][e] = 0;
  __syncthreads();
  for (int i = 0; i < 32; i++){
    int tok = t * 32 + i;
    hist[t][eid[tok]]++;
  }
  __syncthreads();
  int ex[16];
  #pragma unroll
  for (int e = 0; e < 16; e++){
    int v = hist[t][e];
    int s = v;
    #pragma unroll
    for (int d = 1; d < 64; d <<= 1){
      int o = __shfl_up(s, d, 64);
      if (lane >= d) s += o;
    }
    ex[e] = s - v;
    if (lane == 63) wtot[wv][e] = s;
  }
  __syncthreads();
  if (t < 16){
    int run = 0;
    #pragma unroll
    for (int w = 0; w < 4; w++){ int c = wtot[w][t]; wtot[w][t] = run; run += c; }
  }
  __syncthreads();
  #pragma unroll
  for (int e = 0; e < 16; e++) hist[t][e] = ex[e] + wtot[wv][e];
  __syncthreads();
  for (int i = 0; i < 32; i++){
    int tok = t * 32 + i;
    int e = eid[tok];
    int slot = hist[t][e]++;
    if (slot < CAP){
      expert_tok[e * CAP + slot] = tok;
      cw[e * CAP + slot] = gate[tok];
      dropped[tok] = 0;
    } else {
      dropped[tok] = 1;
    }
  }
}

// ---------------- gather x rows -> bf16 [E][C][D] ----------------
__global__ __launch_bounds__(192) void gather_x_kernel(
    const float* __restrict__ x, const int* __restrict__ expert_tok,
    unsigned short* __restrict__ xa)
{
  int ec = blockIdx.x;
  int token = expert_tok[ec];
  int t4 = threadIdx.x * 4;
  ushort4 o;
  if (token >= 0){
    const float4 v = *(const float4*)(x + (size_t)token * DMODEL + t4);
    o.x = f2bf(v.x); o.y = f2bf(v.y); o.z = f2bf(v.z); o.w = f2bf(v.w);
  } else {
    o.x = 0; o.y = 0; o.z = 0; o.w = 0;
  }
  *(ushort4*)(xa + (size_t)ec * DMODEL + t4) = o;
}

// ---- B staging, 64k x 64n f32 tile, 256 threads: thread (nq=tid&15, kq=tid>>4)
// covers cols nq*4..+4, rows kq*4..+4. Writes b64 at chunk (kq>>1)^((R>>3)&7)
// (2-way = free); b128 reads conflict-free with cx = (kk*4+kg)^((R>>3)&7).
static __device__ __forceinline__ void stage64_load(
    const float* __restrict__ g, int ldg, uint2* p, int nq, int kq)
{
  const float* s = g + (size_t)(kq * 4) * ldg + (size_t)nq * 4;
  float4 r0 = *(const float4*)(s);
  float4 r1 = *(const float4*)(s + ldg);
  float4 r2 = *(const float4*)(s + 2 * ldg);
  float4 r3 = *(const float4*)(s + 3 * ldg);
  p[0].x = pk2b(r0.x, r1.x); p[0].y = pk2b(r2.x, r3.x);
  p[1].x = pk2b(r0.y, r1.y); p[1].y = pk2b(r2.y, r3.y);
  p[2].x = pk2b(r0.z, r1.z); p[2].y = pk2b(r2.z, r3.z);
  p[3].x = pk2b(r0.w, r1.w); p[3].y = pk2b(r2.w, r3.w);
}
static __device__ __forceinline__ void stage64_write(
    const uint2* p, unsigned short* __restrict__ lds, int nq, int kq)
{
  #pragma unroll
  for (int j = 0; j < 4; j++){
    int R = nq * 4 + j;
    int c8 = (kq >> 1) ^ ((R >> 3) & 7);
    *(uint2*)(lds + R * BLDP + c8 * 8 + (kq & 1) * 4) = p[j];
  }
}

// ---------------- GEMM1: xa @ W1 (fused cvt) + swiglu -> act bf16 ----------------
// Narrow-n 128m x (64g+64u), 256 thr, LDS 52KB (3 blocks/CU).
// Counted-vmcnt 2-ahead pipeline. ISSUE ORDER IS CORRECTNESS-CRITICAL:
// sched_barrier(0) pins A-gloads BEFORE B-loads so vmcnt(8) retires exactly the
// 4 A gloads (R13 failed: scheduler interleaved the groups -> stale A tiles).
__global__ __launch_bounds__(256, 3) void gemm1_swiglu_kernel(
    const unsigned short* __restrict__ xa,
    const float* __restrict__ W1,
    const float* __restrict__ b1,
    unsigned short* __restrict__ act)
{
  __shared__ unsigned short As  [128 * 64];    // 16 KB, single buffer
  __shared__ unsigned short LBG0[64 * BLDP];   // 9 KB each, B double-buffer
  __shared__ unsigned short LBG1[64 * BLDP];
  __shared__ unsigned short LBU0[64 * BLDP];
  __shared__ unsigned short LBU1[64 * BLDP];
  const int b = blockIdx.x;
  const int w = (b & 7) * 480 + (b >> 3);      // bijective XCD chunking (3840 = 8*480)
  const int mb = w % 5;
  const int nb = (w / 5) % 48;
  const int e  = w / 240;
  const int m0 = mb * 128;
  const int n0 = nb * 64;
  const int tid  = threadIdx.x;
  const int lane = tid & 63;
  const int wv   = tid >> 6;          // 0..3
  const int wr   = (wv >> 1) * 64;
  const int wc   = (wv & 1) * 32;
  const int fr   = lane & 15;
  const int kg   = lane >> 4;
  const int cA   = fr & 7;
  const int nq   = tid & 15;
  const int kq   = tid >> 4;

  const unsigned short* Ag = xa + ((size_t)e * 640 + m0) * 768;
  const float* Bg = W1 + (size_t)e * 768 * 6144 + n0;
  const float* Bu = Bg + 3072;

  const int srow = wv * 8 + (lane >> 3);
  const int scol = (((lane & 7) ^ ((lane >> 3) & 7)) * 8);
  unsigned short* ldsA = As + wv * 512;

  f32x4 accg[4][2], accu[4][2];
  f32x4 zero4 = {0.f, 0.f, 0.f, 0.f};
  #pragma unroll
  for (int m = 0; m < 4; m++)
    #pragma unroll
    for (int n = 0; n < 2; n++){ accg[m][n] = zero4; accu[m][n] = zero4; }

  uint2 g0[4], u0[4], g1[4], u1[4];   // named reg sets (rule #20)
  const int NT = 12;

  // ---- prologue: queue (pinned) = [A(0)x4, B0x8, B1x8]; B1 stays in flight
  #pragma unroll
  for (int c = 0; c < 4; c++)
    gload16(Ag + (size_t)(c * 32 + srow) * 768 + scol, ldsA + c * 2048);
  __builtin_amdgcn_sched_barrier(0);            // A gloads issue first
  stage64_load(Bg, 6144, g0, nq, kq);
  stage64_load(Bu, 6144, u0, nq, kq);
  stage64_load(Bg + (size_t)64 * 6144, 6144, g1, nq, kq);
  stage64_load(Bu + (size_t)64 * 6144, 6144, u1, nq, kq);
  __builtin_amdgcn_sched_barrier(0);            // B loads before writes/wait
  stage64_write(g0, LBG0, nq, kq);
  stage64_write(u0, LBU0, nq, kq);
  asm volatile("s_waitcnt vmcnt(8) lgkmcnt(0)" ::: "memory");
  __builtin_amdgcn_sched_barrier(0);
  __builtin_amdgcn_s_barrier();
  asm volatile("" ::: "memory");

  #define G1_MFMA(LBG, LBU)                                                                \
    _Pragma("unroll")                                                                      \
    for (int kk = 0; kk < 2; kk++){                                                        \
      short8v af[4], bgf[2], buf[2];                                                       \
      _Pragma("unroll")                                                                    \
      for (int m = 0; m < 4; m++)                                                          \
        af[m] = *(const short8v*)(As + (wr + m * 16 + fr) * 64 + (((kk * 4 + kg) ^ cA) * 8)); \
      _Pragma("unroll")                                                                    \
      for (int n = 0; n < 2; n++){                                                         \
        int R = wc + n * 16 + fr;                                                          \
        int cx = (((kk * 4 + kg) ^ ((R >> 3) & 7)) * 8);                                   \
        bgf[n] = *(const short8v*)(LBG + R * BLDP + cx);                                   \
        buf[n] = *(const short8v*)(LBU + R * BLDP + cx);                                   \
      }                                                                                    \
      _Pragma("unroll")                                                                    \
      for (int m = 0; m < 4; m++)                                                          \
        _Pragma("unroll")                                                                  \
        for (int n = 0; n < 2; n++){                                                       \
          accg[m][n] = __builtin_amdgcn_mfma_f32_16x16x32_bf16(af[m], bgf[n], accg[m][n], 0, 0, 0); \
          accu[m][n] = __builtin_amdgcn_mfma_f32_16x16x32_bf16(af[m], buf[n], accu[m][n], 0, 0, 0); \
        }                                                                                  \
    }

  // step T: MFMA on LBc; barrier-1 (__syncthreads drains old B reg-loads);
  // [pinned] issue A(T+1); issue B(T+2); write B(T+1)->LBn;
  // vmcnt(8): A retired, B(T+2) alive across raw barrier-2.
  #define G1_STEP(T, LBGc, LBUc, LBGn, LBUn, WG, WU, LG, LU)                               \
    do {                                                                                   \
      G1_MFMA(LBGc, LBUc)                                                                  \
      if ((T) + 1 < NT){                                                                   \
        __syncthreads();                                                                   \
        _Pragma("unroll")                                                                  \
        for (int c = 0; c < 4; c++)                                                        \
          gload16(Ag + (size_t)(c * 32 + srow) * 768 + ((T) + 1) * 64 + scol,              \
                  ldsA + c * 2048);                                                        \
        __builtin_amdgcn_sched_barrier(0);                                                 \
        if ((T) + 2 < NT){                                                                 \
          stage64_load(Bg + (size_t)((T) + 2) * 64 * 6144, 6144, LG, nq, kq);              \
          stage64_load(Bu + (size_t)((T) + 2) * 64 * 6144, 6144, LU, nq, kq);              \
        }                                                                                  \
        __builtin_amdgcn_sched_barrier(0);                                                 \
        stage64_write(WG, LBGn, nq, kq);                                                   \
        stage64_write(WU, LBUn, nq, kq);                                                   \
        if ((T) + 2 < NT) asm volatile("s_waitcnt vmcnt(8) lgkmcnt(0)" ::: "memory");      \
        else              asm volatile("s_waitcnt vmcnt(0) lgkmcnt(0)" ::: "memory");      \
        __builtin_amdgcn_sched_barrier(0);                                                 \
        __builtin_amdgcn_s_barrier();                                                      \
        asm volatile("" ::: "memory");                                                     \
      }                                                                                    \
    } while (0)

  #pragma unroll
  for (int t = 0; t < NT; t += 2){
    G1_STEP(t,     LBG0, LBU0, LBG1, LBU1, g1, u1, g0, u0);
    G1_STEP(t + 1, LBG1, LBU1, LBG0, LBU0, g0, u0, g1, u1);
  }
  #undef G1_STEP
  #undef G1_MFMA

  // epilogue: (+bias) -> silu(g)*u -> bf16 act
  #pragma unroll
  for (int n = 0; n < 2; n++){
    int col = n0 + wc + n * 16 + fr;
    float b_g = b1[(size_t)e * 6144 + col];
    float b_u = b1[(size_t)e * 6144 + 3072 + col];
    #pragma unroll
    for (int m = 0; m < 4; m++){
      #pragma unroll
      for (int r = 0; r < 4; r++){
        int row = m0 + wr + m * 16 + kg * 4 + r;
        float hg = accg[m][n][r] + b_g;
        float hu = accu[m][n][r] + b_u;
        float s = (hg / (1.0f + __expf(-hg))) * hu;
        act[((size_t)e * 640 + row) * 3072 + col] = f2bf(s);
      }
    }
  }
}

// ---------------- GEMM2: act @ W2 + b2, fused combine scatter, same pipeline ------
__global__ __launch_bounds__(256, 3) void gemm2_kernel(
    const unsigned short* __restrict__ act,
    const float* __restrict__ W2,
    const float* __restrict__ b2,
    const int* __restrict__ expert_tok,
    const float* __restrict__ cw,
    float* __restrict__ out)                 // [N][768]
{
  __shared__ unsigned short As [128 * 64];
  __shared__ unsigned short LB0[64 * BLDP];
  __shared__ unsigned short LB1[64 * BLDP];
  const int b = blockIdx.x;
  const int w = (b & 7) * 120 + (b >> 3);
  const int mb = w % 5;
  const int nb = (w / 5) % 12;
  const int e  = w / 60;
  const int m0 = mb * 128;
  const int n0 = nb * 64;
  const int tid  = threadIdx.x;
  const int lane = tid & 63;
  const int wv   = tid >> 6;
  const int wr   = (wv & 1) * 64;
  const int wc   = (wv >> 1) * 32;
  const int fr   = lane & 15;
  const int kg   = lane >> 4;
  const int cA   = fr & 7;
  const int nq   = tid & 15;
  const int kq   = tid >> 4;

  const unsigned short* Ag = act + ((size_t)e * 640 + m0) * 3072;
  const float* Bg = W2 + (size_t)e * 3072 * 768 + n0;

  const int srow = wv * 8 + (lane >> 3);
  const int scol = (((lane & 7) ^ ((lane >> 3) & 7)) * 8);
  unsigned short* ldsA = As + wv * 512;

  f32x4 acc[4][2];
  f32x4 zero4 = {0.f, 0.f, 0.f, 0.f};
  #pragma unroll
  for (int m = 0; m < 4; m++)
    #pragma unroll
    for (int n = 0; n < 2; n++) acc[m][n] = zero4;

  uint2 p0[4], p1[4];
  const int NT = 48;

  // ---- prologue (pinned order: A x4, then B0 x4, B1 x4)
  #pragma unroll
  for (int c = 0; c < 4; c++)
    gload16(Ag + (size_t)(c * 32 + srow) * 3072 + scol, ldsA + c * 2048);
  __builtin_amdgcn_sched_barrier(0);
  stage64_load(Bg, 768, p0, nq, kq);
  stage64_load(Bg + (size_t)64 * 768, 768, p1, nq, kq);
  __builtin_amdgcn_sched_barrier(0);
  stage64_write(p0, LB0, nq, kq);
  asm volatile("s_waitcnt vmcnt(4) lgkmcnt(0)" ::: "memory");
  __builtin_amdgcn_sched_barrier(0);
  __builtin_amdgcn_s_barrier();
  asm volatile("" ::: "memory");

  #define G2_MFMA(LB)                                                                     \
    _Pragma("unroll")                                                                      \
    for (int kk = 0; kk < 2; kk++){                                                        \
      short8v af[4], bf[2];                                                                \
      _Pragma("unroll")                                                                    \
      for (int m = 0; m < 4; m++)                                                          \
        af[m] = *(const short8v*)(As + (wr + m * 16 + fr) * 64 + (((kk * 4 + kg) ^ cA) * 8)); \
      _Pragma("unroll")                                                                    \
      for (int n = 0; n < 2; n++){                                                         \
        int R = wc + n * 16 + fr;                                                          \
        int cx = (((kk * 4 + kg) ^ ((R >> 3) & 7)) * 8);                                   \
        bf[n] = *(const short8v*)(LB + R * BLDP + cx);                                     \
      }                                                                                    \
      _Pragma("unroll")                                                                    \
      for (int m = 0; m < 4; m++)                                                          \
        _Pragma("unroll")                                                                  \
        for (int n = 0; n < 2; n++)                                                        \
          acc[m][n] = __builtin_amdgcn_mfma_f32_16x16x32_bf16(af[m], bf[n], acc[m][n], 0, 0, 0); \
    }

  #define G2_STEP(T, LBc, LBn, WP, LP)                                                     \
    do {                                                                                   \
      G2_MFMA(LBc)                                                                         \
      if ((T) + 1 < NT){                                                                   \
        __syncthreads();                                                                   \
        _Pragma("unroll")                                                                  \
        for (int c = 0; c < 4; c++)                                                        \
          gload16(Ag + (size_t)(c * 32 + srow) * 3072 + ((T) + 1) * 64 + scol,             \
                  ldsA + c * 2048);                                                        \
        __builtin_amdgcn_sched_barrier(0);                                                 \
        if ((T) + 2 < NT)                                                                  \
          stage64_load(Bg + (size_t)((T) + 2) * 64 * 768, 768, LP, nq, kq);                \
        __builtin_amdgcn_sched_barrier(0);                                                 \
        stage64_write(WP, LBn, nq, kq);                                                    \
        if ((T) + 2 < NT) asm volatile("s_waitcnt vmcnt(4) lgkmcnt(0)" ::: "memory");      \
        else              asm volatile("s_waitcnt vmcnt(0) lgkmcnt(0)" ::: "memory");      \
        __builtin_amdgcn_sched_barrier(0);                                                 \
        __builtin_amdgcn_s_barrier();                                                      \
        asm volatile("" ::: "memory");                                                     \
      }                                                                                    \
    } while (0)

  for (int t = 0; t < NT; t += 2){
    G2_STEP(t,     LB0, LB1, p1, p0);
    G2_STEP(t + 1, LB1, LB0, p0, p1);
  }
  #undef G2_STEP
  #undef G2_MFMA

  float b2v[2];
  #pragma unroll
  for (int n = 0; n < 2; n++) b2v[n] = b2[(size_t)e * 768 + n0 + wc + n * 16 + fr];
  #pragma unroll
  for (int m = 0; m < 4; m++){
    #pragma unroll
    for (int r = 0; r < 4; r++){
      int row = m0 + wr + m * 16 + kg * 4 + r;
      int token = expert_tok[e * CAP + row];
      if (token >= 0){
        float wgt = cw[e * CAP + row];
        #pragma unroll
        for (int n = 0; n < 2; n++){
          int col = n0 + wc + n * 16 + fr;
          out[(size_t)token * 768 + col] = (acc[m][n][r] + b2v[n]) * wgt;
        }
      }
    }
  }
}

// ---------------- dense fallback for dropped tokens only ----------------
__global__ __launch_bounds__(256) void fallback_kernel(
    const float* __restrict__ x,
    const float* __restrict__ W1f, const float* __restrict__ b1f,
    const float* __restrict__ W2f, const float* __restrict__ b2f,
    const int* __restrict__ dropped, float* __restrict__ out)
{
  int t = blockIdx.x;
  if (dropped[t] == 0) return;
  __shared__ float xs[768];
  __shared__ float hs[6144];
  int tid = threadIdx.x;
  for (int d = tid; d < 768; d += 256) xs[d] = x[(size_t)t * 768 + d];
  __syncthreads();
  for (int j = tid; j < 6144; j += 256){
    float a = b1f[j];
    for (int d = 0; d < 768; d++) a += xs[d] * W1f[(size_t)d * 6144 + j];
    hs[j] = a;
  }
  __syncthreads();
  for (int j = tid; j < 3072; j += 256){
    float hg = hs[j], hu = hs[j + 3072];
    hs[j] = (hg / (1.0f + __expf(-hg))) * hu;
  }
  __syncthreads();
  for (int d = tid; d < 768; d += 256){
    float a = b2f[d];
    for (int h = 0; h < 3072; h++) a += hs[h] * W2f[(size_t)h * 768 + d];
    out[(size_t)t * 768 + d] = a;   // FALLBACK_W = 1.0
  }
}

extern "C" void kernel_launch(void* const* d_in, const int* in_sizes, int n_in,
                              void* d_out, int out_size, void* d_ws, size_t ws_size,
                              hipStream_t stream) {
  const float* x   = (const float*)d_in[0];
  const float* Wr  = (const float*)d_in[1];
  const float* W1  = (const float*)d_in[2];
  const float* b1  = (const float*)d_in[3];
  const float* W2  = (const float*)d_in[4];
  const float* b2  = (const float*)d_in[5];
  const float* W1f = (const float*)d_in[6];
  const float* b1f = (const float*)d_in[7];
  const float* W2f = (const float*)d_in[8];
  const float* b2f = (const float*)d_in[9];
  float* out = (float*)d_out;

  char* ws = (char*)d_ws;
  int*            expert_tok = (int*)  (ws + 0);          // 16*640*4 = 40960
  float*          cw         = (float*)(ws + 40960);
  int*            eid        = (int*)  (ws + 81920);
  float*          gate       = (float*)(ws + 114688);
  int*            drop       = (int*)  (ws + 147456);
  unsigned short* xa         = (unsigned short*)(ws + 180224);     // 16*640*768*2  = 15728640
  unsigned short* act        = (unsigned short*)(ws + 15908864);   // 16*640*3072*2 = 62914560
  // total ws use: ~79 MB

  init_tok_kernel<<<40, 256, 0, stream>>>(expert_tok);
  router_kernel<<<2048, 256, 0, stream>>>(x, Wr, eid, gate);
  scan_route_kernel<<<1, 256, 0, stream>>>(eid, gate, expert_tok, cw, drop);
  gather_x_kernel<<<16 * CAP, 192, 0, stream>>>(x, expert_tok, xa);
  gemm1_swiglu_kernel<<<3840, 256, 0, stream>>>(xa, W1, b1, act);
  gemm2_kernel<<<960, 256, 0, stream>>>(act, W2, b2, expert_tok, cw, out);
  fallback_kernel<<<NTOK, 256, 0, stream>>>(x, W1f, b1f, W2f, b2f, drop, out);
}